// Round 2
// baseline (2688.602 us; speedup 1.0000x reference)
//
#include <hip/hip_runtime.h>
#include <hip/hip_bf16.h>

// Problem constants
constexpr int H  = 8;
constexpr int B  = 32;
constexpr int L  = 4096;
constexpr int D  = 64;
constexpr int S  = 45;   // sample_k
constexpr int U  = 45;   // n_top
constexpr int HB = H * B; // 256

// ---------------------------------------------------------------------------
// Kernel 1: sparsity measure M[hb][i] = max_s qk(i,s) - sum_s qk(i,s)/L
// Layout: 256 threads = 16 groups of 16 lanes; each group = one query.
// Lane l holds q[i, 4l..4l+3] (float4). 45 gathered k rows per query.
// ---------------------------------------------------------------------------
__global__ __launch_bounds__(256) void k_probe(const float* __restrict__ q,
                                               const float* __restrict__ k,
                                               const int* __restrict__ sidx,
                                               float* __restrict__ M) {
    int hb   = blockIdx.x >> 8;      // 256 query-chunks per hb
    int qblk = blockIdx.x & 255;
    int g    = threadIdx.x >> 4;     // group 0..15 (block), 0..3 within wave
    int l    = threadIdx.x & 15;     // lane-in-group
    int i    = qblk * 16 + g;        // query index

    const float* qrow = q + ((size_t)hb * L + i) * D;
    float4 qv = *(const float4*)(qrow + l * 4);

    // preload this query's 45 sample indices across the 16 lanes of the group
    const int* ip = sidx + (size_t)i * S;
    int e0 = ip[l];
    int e1 = ip[16 + l];
    int e2 = (32 + l < S) ? ip[32 + l] : 0;

    int gw = (g & 3) << 4;           // group base lane within the wave
    const float* kbase = k + (size_t)hb * L * D;
    float mx = -1e30f, sm = 0.0f;

    for (int s = 0; s < S; ++s) {
        int src = (s < 16) ? e0 : ((s < 32) ? e1 : e2);
        int j = __shfl(src, gw + (s & 15), 64);
        float4 kv = *(const float4*)(kbase + (size_t)j * D + l * 4);
        float p = qv.x * kv.x + qv.y * kv.y + qv.z * kv.z + qv.w * kv.w;
        p += __shfl_xor(p, 8, 64);
        p += __shfl_xor(p, 4, 64);
        p += __shfl_xor(p, 2, 64);
        p += __shfl_xor(p, 1, 64);
        mx = fmaxf(mx, p);
        sm += p;
    }
    if (l == 0) M[(size_t)hb * L + i] = mx - sm * (1.0f / (float)L);
}

// ---------------------------------------------------------------------------
// Kernel 2: top-45 indices of M per (h,b). Iterative argmax, tie -> lower idx.
// ---------------------------------------------------------------------------
__global__ __launch_bounds__(256) void k_topk(const float* __restrict__ M,
                                              int* __restrict__ mtop) {
    __shared__ float sv[L];
    __shared__ float rv[4];
    __shared__ int   ri[4];
    int hb = blockIdx.x;
    const float* Mr = M + (size_t)hb * L;
    for (int t = threadIdx.x; t < L; t += 256) sv[t] = Mr[t];
    __syncthreads();

    for (int t = 0; t < U; ++t) {
        float bv = -1e30f; int bi = 0;
        for (int c = threadIdx.x; c < L; c += 256) {
            float vv = sv[c];
            if (vv > bv) { bv = vv; bi = c; }   // strict > keeps lowest c per thread
        }
        for (int off = 32; off; off >>= 1) {
            float ov = __shfl_down(bv, off, 64);
            int   oi = __shfl_down(bi, off, 64);
            if (ov > bv || (ov == bv && oi < bi)) { bv = ov; bi = oi; }
        }
        int w = threadIdx.x >> 6;
        if ((threadIdx.x & 63) == 0) { rv[w] = bv; ri[w] = bi; }
        __syncthreads();
        if (threadIdx.x == 0) {
            for (int ww = 1; ww < 4; ++ww)
                if (rv[ww] > bv || (rv[ww] == bv && ri[ww] < bi)) { bv = rv[ww]; bi = ri[ww]; }
            mtop[hb * U + t] = bi;
            sv[bi] = -1e30f;
        }
        __syncthreads();
    }
}

// ---------------------------------------------------------------------------
// Kernel 3: per-(h,b) mean of v over L -> vmean[hb][d]
// ---------------------------------------------------------------------------
__global__ __launch_bounds__(256) void k_vmean(const float* __restrict__ v,
                                               float* __restrict__ vmean) {
    int hb = blockIdx.x;
    int d  = threadIdx.x & 63;
    int r  = threadIdx.x >> 6;
    const float* vb = v + (size_t)hb * L * D;
    float s = 0.0f;
    for (int i = r; i < L; i += 4) s += vb[(size_t)i * D + d];
    __shared__ float sm[4][64];
    sm[r][d] = s;
    __syncthreads();
    if (threadIdx.x < 64) {
        float t = sm[0][d] + sm[1][d] + sm[2][d] + sm[3][d];
        vmean[hb * D + d] = t * (1.0f / (float)L);
    }
}

// ---------------------------------------------------------------------------
// Kernel 4: fill entire output with broadcast vmean (float32). 16B/thread.
// ---------------------------------------------------------------------------
__global__ __launch_bounds__(256) void k_fill(const float* __restrict__ vmean,
                                              float* __restrict__ out) {
    size_t g  = (size_t)blockIdx.x * 256 + threadIdx.x;   // HB*L*D/4 threads
    int d0    = (int)(g & 15) * 4;                         // 16 float4 per row
    size_t row = g >> 4;                                   // hb*L + i
    int hb    = (int)(row >> 12);                          // /L
    const float* vm = vmean + hb * D + d0;
    float4 t = *(const float4*)vm;
    *(float4*)(out + row * D + d0) = t;
}

// ---------------------------------------------------------------------------
// Kernel 5: full attention for the 45 selected queries of one (h,b).
// lane = query (45 used of 64); 8 waves split the 4096 keys; online softmax;
// LDS merge across waves; scatter float rows into out.
// ---------------------------------------------------------------------------
constexpr int KW = 8; // waves per block

__global__ __launch_bounds__(512) void k_attn(const float* __restrict__ q,
                                              const float* __restrict__ k,
                                              const float* __restrict__ v,
                                              const int* __restrict__ mtop,
                                              float* __restrict__ out) {
    int hb   = blockIdx.x;
    int w    = threadIdx.x >> 6;
    int lane = threadIdx.x & 63;

    int uq = mtop[hb * U + ((lane < U) ? lane : 0)];
    const float* qrow = q + ((size_t)hb * L + uq) * D;
    float qreg[D];
#pragma unroll
    for (int d = 0; d < D; ++d) qreg[d] = qrow[d] * 0.125f; // fold 1/sqrt(64)

    const float* kb = k + (size_t)hb * L * D;
    const float* vb = v + (size_t)hb * L * D;
    int j0 = w * (L / KW), j1 = j0 + (L / KW);

    float m = -1e30f, lsum = 0.0f;
    float O[D];
#pragma unroll
    for (int d = 0; d < D; ++d) O[d] = 0.0f;

    for (int j = j0; j < j1; ++j) {
        const float* kr = kb + (size_t)j * D;
        float s = 0.0f;
#pragma unroll
        for (int d = 0; d < D; ++d) s = fmaf(qreg[d], kr[d], s);
        const float* vr = vb + (size_t)j * D;
        if (__any(s > m)) {
            float mn = fmaxf(m, s);
            float c  = __expf(m - mn);   // 0 on first key (m=-1e30)
            float p  = __expf(s - mn);
            lsum = lsum * c + p;
#pragma unroll
            for (int d = 0; d < D; ++d) O[d] = fmaf(O[d], c, p * vr[d]);
            m = mn;
        } else {
            float p = __expf(s - m);
            lsum += p;
#pragma unroll
            for (int d = 0; d < D; ++d) O[d] = fmaf(p, vr[d], O[d]);
        }
    }

    // --- merge the 8 waves ---
    __shared__ float wm[KW][64];
    __shared__ float wl[KW][64];
    __shared__ float accO[64][D + 1];
    wm[w][lane] = m;
    wl[w][lane] = lsum;
    __syncthreads();

    float Mstar = -1e30f;
#pragma unroll
    for (int ww = 0; ww < KW; ++ww) Mstar = fmaxf(Mstar, wm[ww][lane]);
    float Ltot = 0.0f;
#pragma unroll
    for (int ww = 0; ww < KW; ++ww) Ltot += __expf(wm[ww][lane] - Mstar) * wl[ww][lane];
    float cw = __expf(m - Mstar);

    for (int ww = 0; ww < KW; ++ww) {
        if (w == ww) {
            if (ww == 0) {
#pragma unroll
                for (int d = 0; d < D; ++d) accO[lane][d] = O[d] * cw;
            } else {
#pragma unroll
                for (int d = 0; d < D; ++d) accO[lane][d] += O[d] * cw;
            }
        }
        __syncthreads();
    }

    if (w == 0 && lane < U) {
        float inv = 1.0f / Ltot;
        float* orow = out + ((size_t)hb * L + uq) * D;
#pragma unroll
        for (int d0 = 0; d0 < D; d0 += 4) {
            float4 t;
            t.x = accO[lane][d0 + 0] * inv;
            t.y = accO[lane][d0 + 1] * inv;
            t.z = accO[lane][d0 + 2] * inv;
            t.w = accO[lane][d0 + 3] * inv;
            *(float4*)(orow + d0) = t;
        }
    }
}

// ---------------------------------------------------------------------------
extern "C" void kernel_launch(void* const* d_in, const int* in_sizes, int n_in,
                              void* d_out, int out_size, void* d_ws, size_t ws_size,
                              hipStream_t stream) {
    const float* q    = (const float*)d_in[0];
    const float* k    = (const float*)d_in[1];
    const float* v    = (const float*)d_in[2];
    const int*   sidx = (const int*)d_in[3];
    float* out = (float*)d_out;

    char* ws = (char*)d_ws;
    float* M     = (float*)ws;                                   // 4 MB
    int*   mtop  = (int*)(ws + (size_t)HB * L * 4);              // 46 KB
    float* vmean = (float*)(ws + (size_t)HB * L * 4 + 65536);    // 64 KB

    k_probe<<<HB * (L / 16), 256, 0, stream>>>(q, k, sidx, M);
    k_topk <<<HB, 256, 0, stream>>>(M, mtop);
    k_vmean<<<HB, 256, 0, stream>>>(v, vmean);
    k_fill <<<HB * (L / 16), 256, 0, stream>>>(vmean, out);   // HB*L*D/4/256
    k_attn <<<HB, 512, 0, stream>>>(q, k, v, mtop, out);
}

// Round 3
// 2497.080 us; speedup vs baseline: 1.0767x; 1.0767x over previous
//
#include <hip/hip_runtime.h>
#include <hip/hip_bf16.h>

// Problem constants
constexpr int H   = 8;
constexpr int B   = 32;
constexpr int SEQ = 4096;
constexpr int D   = 64;
constexpr int S   = 45;   // sample_k
constexpr int U   = 45;   // n_top
constexpr int HB  = H * B; // 256

// ---------------------------------------------------------------------------
// Kernel 1: sparsity measure M[hb][i] = max_s qk(i,s) - sum_s qk(i,s)/SEQ
// 256 threads = 16 groups x 16 lanes; group = one query; lane = float4 of D.
// Sample indices staged in LDS so the 45 gathers pipeline (no shfl in the
// address path).
// ---------------------------------------------------------------------------
__global__ __launch_bounds__(256) void k_probe(const float* __restrict__ q,
                                               const float* __restrict__ k,
                                               const int* __restrict__ sidx,
                                               float* __restrict__ M) {
    __shared__ int sIdx[16][48];
    int hb   = blockIdx.x >> 8;
    int qblk = blockIdx.x & 255;
    int g    = threadIdx.x >> 4;
    int l    = threadIdx.x & 15;
    int i    = qblk * 16 + g;

    const int* ip = sidx + (size_t)i * S;
    sIdx[g][l]      = ip[l];
    sIdx[g][l + 16] = ip[l + 16];
    if (l + 32 < S) sIdx[g][l + 32] = ip[l + 32];
    __syncthreads();

    float4 qv = *(const float4*)(q + ((size_t)hb * SEQ + i) * D + l * 4);
    const float* kbase = k + (size_t)hb * SEQ * D;
    float mx = -1e30f, sm = 0.0f;

#pragma unroll 15
    for (int s = 0; s < S; ++s) {
        int j = sIdx[g][s];
        float4 kv = *(const float4*)(kbase + (size_t)j * D + l * 4);
        float p = qv.x * kv.x + qv.y * kv.y + qv.z * kv.z + qv.w * kv.w;
        p += __shfl_xor(p, 8, 64);
        p += __shfl_xor(p, 4, 64);
        p += __shfl_xor(p, 2, 64);
        p += __shfl_xor(p, 1, 64);
        mx = fmaxf(mx, p);
        sm += p;
    }
    if (l == 0) M[(size_t)hb * SEQ + i] = mx - sm * (1.0f / (float)SEQ);
}

// ---------------------------------------------------------------------------
// Kernel 2: top-45 indices of M per (h,b). Iterative argmax, tie -> lower idx.
// ---------------------------------------------------------------------------
__global__ __launch_bounds__(256) void k_topk(const float* __restrict__ M,
                                              int* __restrict__ mtop) {
    __shared__ float sv[SEQ];
    __shared__ float rv[4];
    __shared__ int   ri[4];
    int hb = blockIdx.x;
    const float* Mr = M + (size_t)hb * SEQ;
    for (int t = threadIdx.x; t < SEQ; t += 256) sv[t] = Mr[t];
    __syncthreads();

    for (int t = 0; t < U; ++t) {
        float bv = -1e30f; int bi = 0;
        for (int c = threadIdx.x; c < SEQ; c += 256) {
            float vv = sv[c];
            if (vv > bv) { bv = vv; bi = c; }
        }
        for (int off = 32; off; off >>= 1) {
            float ov = __shfl_down(bv, off, 64);
            int   oi = __shfl_down(bi, off, 64);
            if (ov > bv || (ov == bv && oi < bi)) { bv = ov; bi = oi; }
        }
        int w = threadIdx.x >> 6;
        if ((threadIdx.x & 63) == 0) { rv[w] = bv; ri[w] = bi; }
        __syncthreads();
        if (threadIdx.x == 0) {
            for (int ww = 1; ww < 4; ++ww)
                if (rv[ww] > bv || (rv[ww] == bv && ri[ww] < bi)) { bv = rv[ww]; bi = ri[ww]; }
            mtop[hb * U + t] = bi;
            sv[bi] = -1e30f;
        }
        __syncthreads();
    }
}

// ---------------------------------------------------------------------------
// Kernel 3: fused per-(h,b) v-mean + broadcast fill of the whole output.
// ---------------------------------------------------------------------------
__global__ __launch_bounds__(1024) void k_vmeanfill(const float* __restrict__ v,
                                                    float* __restrict__ out) {
    int hb = blockIdx.x;
    int d  = threadIdx.x & 63;
    int r  = threadIdx.x >> 6;   // 0..15
    const float* vb = v + (size_t)hb * SEQ * D;
    float s = 0.0f;
    for (int i = r; i < SEQ; i += 16) s += vb[(size_t)i * D + d];
    __shared__ float sm[16][64];
    __shared__ float4 vmean4[16];
    sm[r][d] = s;
    __syncthreads();
    if (threadIdx.x < 64) {
        float t = 0.0f;
#pragma unroll
        for (int rr = 0; rr < 16; ++rr) t += sm[rr][d];
        ((float*)vmean4)[d] = t * (1.0f / (float)SEQ);
    }
    __syncthreads();
    float4 val = vmean4[threadIdx.x & 15];
    float* ob = out + (size_t)hb * SEQ * D;
    for (int t = threadIdx.x; t < SEQ * 16; t += 1024)
        *(float4*)(ob + (size_t)t * 4) = val;
}

// ---------------------------------------------------------------------------
// Kernel 4: attention for the 45 selected queries of one (h,b).
// 768 threads = 12 waves = 3 query-waves x 4 key-splits.
// Wave layout: 16 groups of 4 lanes; group = query, lane = 16-float D-slice.
// 8-key tiles with one rescale per tile; LDS merge of the 4 key-splits.
// ---------------------------------------------------------------------------
constexpr int NKS = 4;

__global__ __launch_bounds__(768) void k_attn(const float* __restrict__ q,
                                              const float* __restrict__ k,
                                              const float* __restrict__ v,
                                              const int* __restrict__ mtop,
                                              float* __restrict__ out) {
    int hb   = blockIdx.x;
    int w    = threadIdx.x >> 6;    // 0..11
    int lane = threadIdx.x & 63;
    int wq   = w % 3;               // query-wave 0..2
    int wk   = w / 3;               // key-split 0..3
    int grp  = lane >> 2;           // 0..15
    int l    = lane & 3;            // 16-float slice id
    int u    = wq * 16 + grp;       // 0..47

    int uq = mtop[hb * U + (u < U ? u : U - 1)];
    const float* qrow = q + ((size_t)hb * SEQ + uq) * D + l * 16;
    float4 qv0 = *(const float4*)(qrow);
    float4 qv1 = *(const float4*)(qrow + 4);
    float4 qv2 = *(const float4*)(qrow + 8);
    float4 qv3 = *(const float4*)(qrow + 12);
    qv0.x *= 0.125f; qv0.y *= 0.125f; qv0.z *= 0.125f; qv0.w *= 0.125f;
    qv1.x *= 0.125f; qv1.y *= 0.125f; qv1.z *= 0.125f; qv1.w *= 0.125f;
    qv2.x *= 0.125f; qv2.y *= 0.125f; qv2.z *= 0.125f; qv2.w *= 0.125f;
    qv3.x *= 0.125f; qv3.y *= 0.125f; qv3.z *= 0.125f; qv3.w *= 0.125f;

    float O[16];
#pragma unroll
    for (int dd = 0; dd < 16; ++dd) O[dd] = 0.0f;
    float m = -1e30f, ls = 0.0f;

    const float* kb = k + (size_t)hb * SEQ * D;
    const float* vb = v + (size_t)hb * SEQ * D;
    int j0 = wk * (SEQ / NKS);

    for (int jt = 0; jt < SEQ / NKS; jt += 8) {
        float s[8];
#pragma unroll
        for (int e = 0; e < 8; ++e) {
            const float* kr = kb + (size_t)(j0 + jt + e) * D + l * 16;
            float4 a0 = *(const float4*)(kr);
            float4 a1 = *(const float4*)(kr + 4);
            float4 a2 = *(const float4*)(kr + 8);
            float4 a3 = *(const float4*)(kr + 12);
            float p = qv0.x*a0.x + qv0.y*a0.y + qv0.z*a0.z + qv0.w*a0.w
                    + qv1.x*a1.x + qv1.y*a1.y + qv1.z*a1.z + qv1.w*a1.w
                    + qv2.x*a2.x + qv2.y*a2.y + qv2.z*a2.z + qv2.w*a2.w
                    + qv3.x*a3.x + qv3.y*a3.y + qv3.z*a3.z + qv3.w*a3.w;
            p += __shfl_xor(p, 2, 64);
            p += __shfl_xor(p, 1, 64);
            s[e] = p;
        }
        float tm = fmaxf(fmaxf(fmaxf(s[0], s[1]), fmaxf(s[2], s[3])),
                         fmaxf(fmaxf(s[4], s[5]), fmaxf(s[6], s[7])));
        float mn = fmaxf(m, tm);
        float c = __expf(m - mn);    // 0 on first tile
        ls *= c;
#pragma unroll
        for (int dd = 0; dd < 16; ++dd) O[dd] *= c;
        m = mn;
#pragma unroll
        for (int e = 0; e < 8; ++e) {
            float pp = __expf(s[e] - m);
            ls += pp;
            const float* vr = vb + (size_t)(j0 + jt + e) * D + l * 16;
            float4 b0 = *(const float4*)(vr);
            float4 b1 = *(const float4*)(vr + 4);
            float4 b2 = *(const float4*)(vr + 8);
            float4 b3 = *(const float4*)(vr + 12);
            O[0]  = fmaf(pp, b0.x, O[0]);  O[1]  = fmaf(pp, b0.y, O[1]);
            O[2]  = fmaf(pp, b0.z, O[2]);  O[3]  = fmaf(pp, b0.w, O[3]);
            O[4]  = fmaf(pp, b1.x, O[4]);  O[5]  = fmaf(pp, b1.y, O[5]);
            O[6]  = fmaf(pp, b1.z, O[6]);  O[7]  = fmaf(pp, b1.w, O[7]);
            O[8]  = fmaf(pp, b2.x, O[8]);  O[9]  = fmaf(pp, b2.y, O[9]);
            O[10] = fmaf(pp, b2.z, O[10]); O[11] = fmaf(pp, b2.w, O[11]);
            O[12] = fmaf(pp, b3.x, O[12]); O[13] = fmaf(pp, b3.y, O[13]);
            O[14] = fmaf(pp, b3.z, O[14]); O[15] = fmaf(pp, b3.w, O[15]);
        }
    }

    // --- merge the 4 key-splits in LDS ---
    __shared__ float smM[NKS][48];
    __shared__ float smL[NKS][48];
    __shared__ float smO[NKS][48][72];   // pad 64->72 dwords (16B aligned, bank spread)
    if (l == 0) { smM[wk][u] = m; smL[wk][u] = ls; }
    {
        float* op = &smO[wk][u][l * 16];
        *(float4*)(op)      = make_float4(O[0],  O[1],  O[2],  O[3]);
        *(float4*)(op + 4)  = make_float4(O[4],  O[5],  O[6],  O[7]);
        *(float4*)(op + 8)  = make_float4(O[8],  O[9],  O[10], O[11]);
        *(float4*)(op + 12) = make_float4(O[12], O[13], O[14], O[15]);
    }
    __syncthreads();

    int tu = threadIdx.x >> 4;        // 0..47
    int d0 = (threadIdx.x & 15) * 4;
    if (tu < U) {
        float Ms = fmaxf(fmaxf(smM[0][tu], smM[1][tu]), fmaxf(smM[2][tu], smM[3][tu]));
        float Lt = 0.0f;
        float ax = 0.0f, ay = 0.0f, az = 0.0f, aw = 0.0f;
#pragma unroll
        for (int p = 0; p < NKS; ++p) {
            float wgt = __expf(smM[p][tu] - Ms);
            Lt += wgt * smL[p][tu];
            float4 o = *(const float4*)&smO[p][tu][d0];
            ax = fmaf(wgt, o.x, ax); ay = fmaf(wgt, o.y, ay);
            az = fmaf(wgt, o.z, az); aw = fmaf(wgt, o.w, aw);
        }
        float inv = 1.0f / Lt;
        int uq2 = mtop[hb * U + tu];
        float4 r = make_float4(ax * inv, ay * inv, az * inv, aw * inv);
        *(float4*)(out + ((size_t)hb * SEQ + uq2) * D + d0) = r;
    }
}

// ---------------------------------------------------------------------------
extern "C" void kernel_launch(void* const* d_in, const int* in_sizes, int n_in,
                              void* d_out, int out_size, void* d_ws, size_t ws_size,
                              hipStream_t stream) {
    const float* q    = (const float*)d_in[0];
    const float* k    = (const float*)d_in[1];
    const float* v    = (const float*)d_in[2];
    const int*   sidx = (const int*)d_in[3];
    float* out = (float*)d_out;

    char* ws = (char*)d_ws;
    float* M    = (float*)ws;                         // 4 MB
    int*   mtop = (int*)(ws + (size_t)HB * SEQ * 4);  // 46 KB

    k_probe    <<<HB * (SEQ / 16), 256, 0, stream>>>(q, k, sidx, M);
    k_topk     <<<HB, 256,  0, stream>>>(M, mtop);
    k_vmeanfill<<<HB, 1024, 0, stream>>>(v, out);
    k_attn     <<<HB, 768,  0, stream>>>(q, k, v, mtop, out);
}